// Round 9
// baseline (309.104 us; speedup 1.0000x reference)
//
#include <hip/hip_runtime.h>
#include <hip/hip_bf16.h>

typedef unsigned short u16;
typedef unsigned long long u64;
typedef __bf16 bf16x8 __attribute__((ext_vector_type(8)));
typedef float f32x4 __attribute__((ext_vector_type(4)));
typedef float f32x2 __attribute__((ext_vector_type(2)));

#define AS1 __attribute__((address_space(1)))
#define AS3 __attribute__((address_space(3)))
#define GLL16(gp, lp) __builtin_amdgcn_global_load_lds((AS1 const unsigned int*)(gp), (AS3 unsigned int*)(lp), 16, 0, 0)

__device__ __forceinline__ u16 f2bf(float f) {
    unsigned u = __builtin_bit_cast(unsigned, f);
    unsigned r = u + 0x7FFFu + ((u >> 16) & 1u);
    return (u16)(r >> 16);
}

// ---------------- mask dtype detector ----------------
// flag: 0=u8(bool), 1=i32, 2=f32, 3=bf16
__global__ void detect_kernel(const unsigned char* __restrict__ m, int* __restrict__ flag) {
    __shared__ int cnt1;
    __shared__ int big;
    if (threadIdx.x == 0) { cnt1 = 0; big = 0; }
    __syncthreads();
    int c1 = 0, bg = 0;
    for (int i = threadIdx.x; i < 16384; i += 256) {
        unsigned char v = m[i];
        if (v) {
            if ((i & 3) == 1) c1++;
            if (v > 1) bg++;
        }
    }
    atomicAdd(&cnt1, c1);
    atomicAdd(&big, bg);
    __syncthreads();
    if (threadIdx.x == 0) {
        int f;
        if (big == 0) f = cnt1 ? 0 : 1;
        else          f = cnt1 ? 3 : 2;
        *flag = f;
    }
}

// ---------------- mask -> packed bitmask (bit L = k-col L within 64-block) ----------------
#define MN_LOOP(PRED)                                                     \
    for (int row = wave; row < 65536; row += nw) {                        \
        size_t base = (size_t)row * 1024;                                 \
        u64 myw = 0;                                                      \
        _Pragma("unroll")                                                 \
        for (int kb = 0; kb < 16; ++kb) {                                 \
            size_t gi = base + kb * 64 + lane;                            \
            bool p = (PRED);                                              \
            u64 w = __ballot(p);                                          \
            if (lane == kb) myw = w;                                      \
        }                                                                 \
        if (lane < 16) MB[(size_t)row * 16 + lane] = myw;                 \
    }

__global__ __launch_bounds__(256) void masknorm_kernel(const void* __restrict__ mp,
                                                       const int* __restrict__ flagp,
                                                       u64* __restrict__ MB) {
    const int flag = *flagp;
    const int lane = threadIdx.x & 63;
    const int wave = blockIdx.x * 4 + (threadIdx.x >> 6);
    const int nw = gridDim.x * 4;
    if (flag == 0) {
        const unsigned char* m8 = (const unsigned char*)mp;
        MN_LOOP(m8[gi] != 0)
    } else if (flag == 1) {
        const int* m32 = (const int*)mp;
        MN_LOOP(m32[gi] != 0)
    } else if (flag == 2) {
        const unsigned* mf = (const unsigned*)mp;
        MN_LOOP((mf[gi] << 1) != 0)
    } else {
        const u16* mb = (const u16*)mp;
        MN_LOOP((mb[gi] & 0x7FFF) != 0)
    }
}

// ---------------- f32 -> bf16 cast of Q/K/V inputs ----------------
__global__ void cast3_kernel(const float* __restrict__ q, const float* __restrict__ k,
                             const float* __restrict__ v, u16* __restrict__ xq,
                             u16* __restrict__ xk, u16* __restrict__ xv) {
    const int n4 = 4 * 1024 * 1024 / 4;
    int stride = gridDim.x * blockDim.x;
    for (int i = blockIdx.x * blockDim.x + threadIdx.x; i < n4; i += stride) {
        float4 a = ((const float4*)q)[i];
        float4 b = ((const float4*)k)[i];
        float4 c = ((const float4*)v)[i];
        ((ushort4*)xq)[i] = make_ushort4(f2bf(a.x), f2bf(a.y), f2bf(a.z), f2bf(a.w));
        ((ushort4*)xk)[i] = make_ushort4(f2bf(b.x), f2bf(b.y), f2bf(b.z), f2bf(b.w));
        ((ushort4*)xv)[i] = make_ushort4(f2bf(c.x), f2bf(c.y), f2bf(c.z), f2bf(c.w));
    }
}

// ---------------- weight transpose + cast ----------------
__global__ __launch_bounds__(256) void wtrans_kernel(
    const float* __restrict__ W0, const float* __restrict__ W1,
    const float* __restrict__ W2, const float* __restrict__ W3,
    u16* __restrict__ T0, u16* __restrict__ T1, u16* __restrict__ T2, u16* __restrict__ T3) {
    const float* W = (blockIdx.z == 0) ? W0 : (blockIdx.z == 1) ? W1 : (blockIdx.z == 2) ? W2 : W3;
    u16* T = (blockIdx.z == 0) ? T0 : (blockIdx.z == 1) ? T1 : (blockIdx.z == 2) ? T2 : T3;
    __shared__ float t[64][65];
    const int n0 = blockIdx.x * 64, k0 = blockIdx.y * 64;
    const int tx = threadIdx.x, ty = threadIdx.y;
    for (int j = ty; j < 64; j += 4) t[j][tx] = W[(size_t)(k0 + j) * 1024 + n0 + tx];
    __syncthreads();
    for (int j = ty; j < 64; j += 4) T[(size_t)(n0 + j) * 1024 + k0 + tx] = f2bf(t[tx][j]);
}

// ---------------- merged QKV GEMM: z=0 Q (scaled), z=1 K, z=2 V (transposed out) ----------------
__global__ __launch_bounds__(256) void qkv_gemm(
    const u16* __restrict__ XQ, const u16* __restrict__ XK, const u16* __restrict__ XV,
    const u16* __restrict__ WQT, const u16* __restrict__ WKT, const u16* __restrict__ WVT,
    const float* __restrict__ bq, const float* __restrict__ bk, const float* __restrict__ bv,
    u16* __restrict__ QS, u16* __restrict__ KS, u16* __restrict__ VT) {
    __shared__ __align__(16) u16 lsA[128 * 64];
    __shared__ __align__(16) u16 lsB[128 * 64];
    const int z = blockIdx.z;
    const u16* A  = (z == 0) ? XQ : (z == 1) ? XK : XV;
    const u16* Bt = (z == 0) ? WQT : (z == 1) ? WKT : WVT;
    const float* bias = (z == 0) ? bq : (z == 1) ? bk : bv;
    const int tid = threadIdx.x, lane = tid & 63, wid = tid >> 6;
    const int bm = blockIdx.y, bn = blockIdx.x;
    const int wr = wid >> 1, wc = wid & 1;
    const int l15 = lane & 15, l4 = lane >> 4;
    f32x4 acc[4][4] = {};
    const int cbase = wid * 256;
    for (int t = 0; t < 16; ++t) {
        __syncthreads();
        for (int j = 0; j < 4; ++j) {
            int c = cbase + j * 64 + lane;
            int row = c >> 3, off = (c & 7) * 8;
            GLL16(A + (size_t)(bm * 128 + row) * 1024 + t * 64 + off, lsA + (size_t)(cbase + j * 64) * 8);
            GLL16(Bt + (size_t)(bn * 128 + row) * 1024 + t * 64 + off, lsB + (size_t)(cbase + j * 64) * 8);
        }
        __syncthreads();
        for (int kk = 0; kk < 2; ++kk) {
            bf16x8 af[4], bfr[4];
            for (int m = 0; m < 4; ++m)
                af[m] = *(const bf16x8*)(lsA + (wr * 64 + m * 16 + l15) * 64 + kk * 32 + l4 * 8);
            for (int n = 0; n < 4; ++n)
                bfr[n] = *(const bf16x8*)(lsB + (wc * 64 + n * 16 + l15) * 64 + kk * 32 + l4 * 8);
            for (int m = 0; m < 4; ++m)
                for (int n = 0; n < 4; ++n)
                    acc[m][n] = __builtin_amdgcn_mfma_f32_16x16x32_bf16(af[m], bfr[n], acc[m][n], 0, 0, 0);
        }
    }
    const float scale = (z == 0) ? 0.125f : 1.0f;
    for (int n = 0; n < 4; ++n) {
        int c = bn * 128 + wc * 64 + n * 16 + l15;
        float bv_ = bias[c];
        for (int m = 0; m < 4; ++m) {
            for (int j = 0; j < 4; ++j) {
                int r = bm * 128 + wr * 64 + m * 16 + l4 * 4 + j;
                float v = acc[m][n][j];
                if (z == 2) {
                    int bb = r >> 10, k = r & 1023, h = c >> 6, d = c & 63;
                    VT[((size_t)((bb * 16 + h) * 64 + d)) * 1024 + k] = f2bf(v + bv_);
                } else {
                    u16* outp = (z == 0) ? QS : KS;
                    outp[(size_t)r * 1024 + c] = f2bf((v + bv_) * scale);
                }
            }
        }
    }
}

// ---------------- output-projection GEMM (+bias +residual, f32 out) ----------------
__global__ __launch_bounds__(256) void gemm_out(
    const u16* __restrict__ A, const u16* __restrict__ Bt, const float* __restrict__ bias,
    float* __restrict__ outp, const float* __restrict__ resid) {
    __shared__ __align__(16) u16 lsA[128 * 64];
    __shared__ __align__(16) u16 lsB[128 * 64];
    const int tid = threadIdx.x, lane = tid & 63, wid = tid >> 6;
    const int bm = blockIdx.y, bn = blockIdx.x;
    const int wr = wid >> 1, wc = wid & 1;
    const int l15 = lane & 15, l4 = lane >> 4;
    f32x4 acc[4][4] = {};
    const int cbase = wid * 256;
    for (int t = 0; t < 16; ++t) {
        __syncthreads();
        for (int j = 0; j < 4; ++j) {
            int c = cbase + j * 64 + lane;
            int row = c >> 3, off = (c & 7) * 8;
            GLL16(A + (size_t)(bm * 128 + row) * 1024 + t * 64 + off, lsA + (size_t)(cbase + j * 64) * 8);
            GLL16(Bt + (size_t)(bn * 128 + row) * 1024 + t * 64 + off, lsB + (size_t)(cbase + j * 64) * 8);
        }
        __syncthreads();
        for (int kk = 0; kk < 2; ++kk) {
            bf16x8 af[4], bfr[4];
            for (int m = 0; m < 4; ++m)
                af[m] = *(const bf16x8*)(lsA + (wr * 64 + m * 16 + l15) * 64 + kk * 32 + l4 * 8);
            for (int n = 0; n < 4; ++n)
                bfr[n] = *(const bf16x8*)(lsB + (wc * 64 + n * 16 + l15) * 64 + kk * 32 + l4 * 8);
            for (int m = 0; m < 4; ++m)
                for (int n = 0; n < 4; ++n)
                    acc[m][n] = __builtin_amdgcn_mfma_f32_16x16x32_bf16(af[m], bfr[n], acc[m][n], 0, 0, 0);
        }
    }
    for (int n = 0; n < 4; ++n) {
        int c = bn * 128 + wc * 64 + n * 16 + l15;
        float bv = bias[c];
        for (int m = 0; m < 4; ++m)
            for (int j = 0; j < 4; ++j) {
                int r = bm * 128 + wr * 64 + m * 16 + l4 * 4 + j;
                outp[(size_t)r * 1024 + c] = acc[m][n][j] + bv + resid[(size_t)r * 1024 + c];
            }
    }
}

// ---------------- fused geometry attention v7: 2-tiles-ahead 3-buffer counted pipeline ----------------
// KVBLK=32, THREE K/V LDS buffers (named, static). Body t: issue stage(t+2) -> issue
// geom/mask(t+1) regs -> compute(t) [setprio around MFMA clusters] -> vmcnt(#issued this
// body) -> s_barrier. The wait retires everything OLDER than this body's issues, i.e.
// stage(t+1) from body t-1 (a full body of slack covers HBM latency even under congestion).
// Per body 10 vmem ops (2 GLL16 + 4 geom f32x2 + 4 mask u32); body 30 has no stage -> vmcnt(8).
// Buffer rotation t%3 and A/B reg parity are compile-time per position (6-body loop x5 + 2 epi).
__global__ __launch_bounds__(256, 4) void attn_kernel(
    const u16* __restrict__ Qs, const u16* __restrict__ Ks, const u16* __restrict__ Vt,
    const float* __restrict__ geom, const u64* __restrict__ MBw,
    u16* __restrict__ AO) {
    // u16 layout: [0,6144) K bufs 3 x [32][64]; [6144,12288) V bufs 3 x [64][32];
    // [12288,14336) pbuf 4 waves x [16][32]
    __shared__ __align__(16) u16 lds[14336];

    const int g = blockIdx.x;
    const int tt = (g & 7) * 128 + (g >> 3);        // XCD swizzle (1024 % 8 == 0, bijective)
    const int qb = tt & 15;
    const int bhid = tt >> 4;
    const int b = bhid >> 4, h = bhid & 15;
    const int q0 = qb * 64;

    const int tid = threadIdx.x, lane = tid & 63, wid = tid >> 6;
    const int l15 = lane & 15, l4 = lane >> 4;
    const int qrow = q0 + wid * 16;
    const size_t bh = (size_t)bhid;

    const u16* qp = Qs + (size_t)(b * 1024 + qrow + l15) * 1024 + h * 64 + l4 * 8;
    bf16x8 aq0 = *(const bf16x8*)qp;
    bf16x8 aq1 = *(const bf16x8*)(qp + 32);

    // staging sources (pre-swizzled global addr; LDS dest linear = wave base + lane*16B)
    const int kr = tid >> 3, ks = tid & 7;                  // K: LDS row 0..31, 16B slot 0..7
    const int kgr = (kr & 15) * 2 + (kr >> 4);              // LDS row kr <- global k-row kgr
    const u16* ksrc = Ks + (size_t)(b * 1024 + kgr) * 1024 + h * 64 + ((ks ^ ((kr >> 1) & 7)) * 8);
    const int vr = tid >> 2, vs = tid & 3;                  // V: d-row 0..63, 16B slot 0..3
    const u16* vsrc = Vt + (bh * 64 + vr) * 1024 + ((vs ^ ((vr >> 1) & 3)) * 8);
    u16* const KD0 = lds + 0    + wid * 512;
    u16* const KD1 = lds + 2048 + wid * 512;
    u16* const KD2 = lds + 4096 + wid * 512;
    u16* const VD0 = lds + 6144 + 0    + wid * 512;
    u16* const VD1 = lds + 6144 + 2048 + wid * 512;
    u16* const VD2 = lds + 6144 + 4096 + wid * 512;
    u16* const pw  = lds + 12288 + wid * 512;

    const float* gbase = geom + (bh * 1024 + qrow + l4 * 4) * 1024 + l15 * 2;
    const unsigned* mb32 = (const unsigned*)(MBw + (bh * 1024 + qrow + l4 * 4) * 16);

    f32x4 o[4] = {};
    float m_run[4], l_run[4];
#pragma unroll
    for (int j = 0; j < 4; ++j) { m_run[j] = -1e30f; l_run[j] = 0.f; }

    f32x2 gpA[4], gpB[4];
    unsigned mkA[4], mkB[4];

    // prologue: stage tiles 0,1; geom/mask(0); vmcnt(10) retires stage(0)'s 2 GLL16 only.
    GLL16(ksrc, KD0);
    GLL16(vsrc, VD0);
    GLL16(ksrc + 32768, KD1);
    GLL16(vsrc + 32, VD1);
    __builtin_amdgcn_sched_barrier(0);
#pragma unroll
    for (int j = 0; j < 4; ++j) {
        gpA[j] = *(const f32x2*)(gbase + j * 1024);
        mkA[j] = mb32[j * 32];
    }
    __builtin_amdgcn_sched_barrier(0);
    asm volatile("s_waitcnt vmcnt(10)" ::: "memory");
    __builtin_amdgcn_sched_barrier(0);
    __builtin_amdgcn_s_barrier();
    __builtin_amdgcn_sched_barrier(0);

#define BODY(T, GC, GN, MC, MN, KBC, VBC, KDN, VDN, WSTR)                                \
    do {                                                                                 \
        if ((T) + 2 < 32) {                                                              \
            GLL16(ksrc + (size_t)((T) + 2) * 32768, KDN);                                \
            GLL16(vsrc + ((T) + 2) * 32, VDN);                                           \
            __builtin_amdgcn_sched_barrier(0);                                           \
        }                                                                                \
        if ((T) + 1 < 32) {                                                              \
            _Pragma("unroll")                                                            \
            for (int j = 0; j < 4; ++j) {                                                \
                GN[j] = *(const f32x2*)(gbase + j * 1024 + ((T) + 1) * 32);              \
                MN[j] = mb32[j * 32 + (T) + 1];                                          \
            }                                                                            \
            __builtin_amdgcn_sched_barrier(0);                                           \
        }                                                                                \
        f32x4 s0, s1;                                                                    \
        __builtin_amdgcn_s_setprio(1);                                                   \
        {                                                                                \
            const int rr = l15, swz = (rr >> 1) & 7;                                     \
            bf16x8 k0 = *(const bf16x8*)((KBC) + rr * 64 + ((l4 ^ swz) * 8));            \
            bf16x8 k1 = *(const bf16x8*)((KBC) + rr * 64 + (((4 + l4) ^ swz) * 8));      \
            f32x4 z = {};                                                                \
            z = __builtin_amdgcn_mfma_f32_16x16x32_bf16(aq0, k0, z, 0, 0, 0);            \
            s0 = __builtin_amdgcn_mfma_f32_16x16x32_bf16(aq1, k1, z, 0, 0, 0);           \
        }                                                                                \
        {                                                                                \
            const int rr = 16 + l15, swz = (rr >> 1) & 7;                                \
            bf16x8 k0 = *(const bf16x8*)((KBC) + rr * 64 + ((l4 ^ swz) * 8));            \
            bf16x8 k1 = *(const bf16x8*)((KBC) + rr * 64 + (((4 + l4) ^ swz) * 8));      \
            f32x4 z = {};                                                                \
            z = __builtin_amdgcn_mfma_f32_16x16x32_bf16(aq0, k0, z, 0, 0, 0);            \
            s1 = __builtin_amdgcn_mfma_f32_16x16x32_bf16(aq1, k1, z, 0, 0, 0);           \
        }                                                                                \
        __builtin_amdgcn_s_setprio(0);                                                   \
        float sclv[4];                                                                   \
        _Pragma("unroll")                                                                \
        for (int j = 0; j < 4; ++j) {                                                    \
            float a0 = s0[j], a1 = s1[j];                                                \
            float mt = fmaxf(a0, a1);                                                    \
            mt = fmaxf(mt, __shfl_xor(mt, 1, 16));                                       \
            mt = fmaxf(mt, __shfl_xor(mt, 2, 16));                                       \
            mt = fmaxf(mt, __shfl_xor(mt, 4, 16));                                       \
            mt = fmaxf(mt, __shfl_xor(mt, 8, 16));                                       \
            float mn = fmaxf(m_run[j], mt);                                              \
            float scl = __expf(m_run[j] - mn);                                           \
            m_run[j] = mn;                                                               \
            unsigned mb2 = (MC[j] >> (l15 * 2)) & 3u;                                    \
            f32x2 gv = GC[j];                                                            \
            float p0 = (mb2 & 1u) ? 0.f : __expf(a0 - mn) * fmaxf(gv[0], 1e-6f);         \
            float p1 = (mb2 & 2u) ? 0.f : __expf(a1 - mn) * fmaxf(gv[1], 1e-6f);         \
            float rs = p0 + p1;                                                          \
            rs += __shfl_xor(rs, 1, 16);                                                 \
            rs += __shfl_xor(rs, 2, 16);                                                 \
            rs += __shfl_xor(rs, 4, 16);                                                 \
            rs += __shfl_xor(rs, 8, 16);                                                 \
            l_run[j] = l_run[j] * scl + rs;                                              \
            sclv[j] = scl;                                                               \
            const int row = l4 * 4 + j;                                                  \
            const int slot4 = (l15 & 3) | ((((l15 >> 2) ^ l4) & 3) << 2);                \
            unsigned pk = (unsigned)f2bf(p0) | ((unsigned)f2bf(p1) << 16);               \
            *(unsigned*)(pw + row * 32 + slot4 * 2) = pk;                                \
        }                                                                                \
        _Pragma("unroll")                                                                \
        for (int df = 0; df < 4; ++df) {                                                 \
            f32x4 tv = o[df];                                                            \
            _Pragma("unroll")                                                            \
            for (int j = 0; j < 4; ++j) tv[j] *= sclv[j];                                \
            o[df] = tv;                                                                  \
        }                                                                                \
        {                                                                                \
            const int blk = (l4 ^ (l15 >> 2)) & 3;                                       \
            bf16x8 pa = *(const bf16x8*)(pw + l15 * 32 + blk * 8);                       \
            __builtin_amdgcn_s_setprio(1);                                               \
            _Pragma("unroll")                                                            \
            for (int df = 0; df < 4; ++df) {                                             \
                const int rr = df * 16 + l15, vswz = (rr >> 1) & 3;                      \
                bf16x8 v0 = *(const bf16x8*)((VBC) + rr * 32 + ((l4 ^ vswz) * 8));       \
                o[df] = __builtin_amdgcn_mfma_f32_16x16x32_bf16(pa, v0, o[df], 0, 0, 0); \
            }                                                                            \
            __builtin_amdgcn_s_setprio(0);                                               \
        }                                                                                \
        if ((T) + 1 < 32) {                                                              \
            asm volatile(WSTR ::: "memory");                                             \
            __builtin_amdgcn_sched_barrier(0);                                           \
            __builtin_amdgcn_s_barrier();                                                \
            __builtin_amdgcn_sched_barrier(0);                                           \
        }                                                                                \
    } while (0)

    for (int it = 0; it < 5; ++it) {
        const int t0 = it * 6;
        BODY(t0 + 0, gpA, gpB, mkA, mkB, (lds + 0),    (lds + 6144),        KD2, VD2, "s_waitcnt vmcnt(10)");
        BODY(t0 + 1, gpB, gpA, mkB, mkA, (lds + 2048), (lds + 6144 + 2048), KD0, VD0, "s_waitcnt vmcnt(10)");
        BODY(t0 + 2, gpA, gpB, mkA, mkB, (lds + 4096), (lds + 6144 + 4096), KD1, VD1, "s_waitcnt vmcnt(10)");
        BODY(t0 + 3, gpB, gpA, mkB, mkA, (lds + 0),    (lds + 6144),        KD2, VD2, "s_waitcnt vmcnt(10)");
        BODY(t0 + 4, gpA, gpB, mkA, mkB, (lds + 2048), (lds + 6144 + 2048), KD0, VD0, "s_waitcnt vmcnt(10)");
        BODY(t0 + 5, gpB, gpA, mkB, mkA, (lds + 4096), (lds + 6144 + 4096), KD1, VD1, "s_waitcnt vmcnt(10)");
    }
    // epilogue bodies: t=30 (no stage -> vmcnt(8)), t=31 (no stage/regs/barrier)
    BODY(30, gpA, gpB, mkA, mkB, (lds + 0),    (lds + 6144),        KD2, VD2, "s_waitcnt vmcnt(8)");
    BODY(31, gpB, gpA, mkB, mkA, (lds + 2048), (lds + 6144 + 2048), KD0, VD0, "s_waitcnt vmcnt(8)");
#undef BODY

    // epilogue: coalesced AO store via wave-private pbuf (full 64B lines)
    float inv[4];
#pragma unroll
    for (int j = 0; j < 4; ++j) inv[j] = 1.0f / l_run[j];
#pragma unroll
    for (int p = 0; p < 2; ++p) {
#pragma unroll
        for (int df2 = 0; df2 < 2; ++df2) {
            const int df = p * 2 + df2;
#pragma unroll
            for (int j = 0; j < 4; ++j)
                pw[(l4 * 4 + j) * 32 + df2 * 16 + l15] = f2bf(o[df][j] * inv[j]);
        }
        const int er = lane >> 2, ec = lane & 3;
        bf16x8 val = *(const bf16x8*)(pw + er * 32 + ec * 8);
        *(bf16x8*)(AO + (size_t)(b * 1024 + qrow + er) * 1024 + h * 64 + p * 32 + ec * 8) = val;
    }
}

// ---------------- LayerNorm over rows of Y (f32) ----------------
__global__ __launch_bounds__(256) void ln_kernel(const float* __restrict__ Y,
                                                 const float* __restrict__ gamma,
                                                 const float* __restrict__ beta,
                                                 float* __restrict__ out) {
    __shared__ float red[8];
    const int r = blockIdx.x, tid = threadIdx.x, lane = tid & 63, wid = tid >> 6;
    float4 v = ((const float4*)(Y + (size_t)r * 1024))[tid];
    float s = v.x + v.y + v.z + v.w;
    float q = v.x * v.x + v.y * v.y + v.z * v.z + v.w * v.w;
    for (int d = 1; d < 64; d <<= 1) {
        s += __shfl_xor(s, d, 64);
        q += __shfl_xor(q, d, 64);
    }
    if (lane == 0) { red[wid] = s; red[4 + wid] = q; }
    __syncthreads();
    float ts = red[0] + red[1] + red[2] + red[3];
    float tq = red[4] + red[5] + red[6] + red[7];
    float mu = ts * (1.f / 1024.f);
    float var = tq * (1.f / 1024.f) - mu * mu;
    float rstd = rsqrtf(var + 1e-5f);
    float4 gg = ((const float4*)gamma)[tid];
    float4 be = ((const float4*)beta)[tid];
    float4 ov;
    ov.x = (v.x - mu) * rstd * gg.x + be.x;
    ov.y = (v.y - mu) * rstd * gg.y + be.y;
    ov.z = (v.z - mu) * rstd * gg.z + be.z;
    ov.w = (v.w - mu) * rstd * gg.w + be.w;
    ((float4*)(out + (size_t)r * 1024))[tid] = ov;
}

extern "C" void kernel_launch(void* const* d_in, const int* in_sizes, int n_in,
                              void* d_out, int out_size, void* d_ws, size_t ws_size,
                              hipStream_t stream) {
    const float* queries = (const float*)d_in[0];
    const float* keys    = (const float*)d_in[1];
    const float* values  = (const float*)d_in[2];
    const float* geom    = (const float*)d_in[3];
    const void*  mask    = d_in[4];
    const float* Wq = (const float*)d_in[5];  const float* bq = (const float*)d_in[6];
    const float* Wk = (const float*)d_in[7];  const float* bk = (const float*)d_in[8];
    const float* Wv = (const float*)d_in[9];  const float* bv = (const float*)d_in[10];
    const float* Wo = (const float*)d_in[11]; const float* bo = (const float*)d_in[12];
    const float* gamma = (const float*)d_in[13];
    const float* beta  = (const float*)d_in[14];

    char* ws = (char*)d_ws;
    const size_t MB_ = 1024 * 1024;
    u16* XQ  = (u16*)(ws + 0);
    u16* XK  = (u16*)(ws + 8 * MB_);
    u16* XV  = (u16*)(ws + 16 * MB_);
    u16* WQT = (u16*)(ws + 24 * MB_);
    u16* WKT = (u16*)(ws + 26 * MB_);
    u16* WVT = (u16*)(ws + 28 * MB_);
    u16* WOT = (u16*)(ws + 30 * MB_);
    u16* QS  = (u16*)(ws + 32 * MB_);
    u16* KS  = (u16*)(ws + 40 * MB_);
    u16* VT  = (u16*)(ws + 48 * MB_);
    u16* AO  = (u16*)(ws + 56 * MB_);
    u64* MBITS = (u64*)(ws + 16 * MB_);  // reuses XV (dead after qkv_gemm)
    float* Y = (float*)(ws + 0);         // reuses XQ/XK region (dead by then)
    int* FLAG = (int*)(ws + 64 * MB_);

    detect_kernel<<<1, 256, 0, stream>>>((const unsigned char*)mask, FLAG);
    cast3_kernel<<<1024, 256, 0, stream>>>(queries, keys, values, XQ, XK, XV);
    wtrans_kernel<<<dim3(16, 16, 4), dim3(64, 4), 0, stream>>>(Wq, Wk, Wv, Wo, WQT, WKT, WVT, WOT);
    qkv_gemm<<<dim3(8, 32, 3), 256, 0, stream>>>(XQ, XK, XV, WQT, WKT, WVT, bq, bk, bv, QS, KS, VT);
    masknorm_kernel<<<4096, 256, 0, stream>>>(mask, FLAG, MBITS);
    attn_kernel<<<1024, 256, 0, stream>>>(QS, KS, VT, geom, MBITS, AO);
    gemm_out<<<dim3(8, 32), 256, 0, stream>>>(AO, WOT, bo, Y, queries);
    ln_kernel<<<4096, 256, 0, stream>>>(Y, gamma, beta, (float*)d_out);
}

// Round 10
// 274.357 us; speedup vs baseline: 1.1266x; 1.1266x over previous
//
#include <hip/hip_runtime.h>
#include <hip/hip_bf16.h>

typedef unsigned short u16;
typedef unsigned long long u64;
typedef __bf16 bf16x8 __attribute__((ext_vector_type(8)));
typedef float f32x4 __attribute__((ext_vector_type(4)));
typedef float f32x2 __attribute__((ext_vector_type(2)));

#define AS1 __attribute__((address_space(1)))
#define AS3 __attribute__((address_space(3)))
#define GLL16(gp, lp) __builtin_amdgcn_global_load_lds((AS1 const unsigned int*)(gp), (AS3 unsigned int*)(lp), 16, 0, 0)

__device__ __forceinline__ u16 f2bf(float f) {
    unsigned u = __builtin_bit_cast(unsigned, f);
    unsigned r = u + 0x7FFFu + ((u >> 16) & 1u);
    return (u16)(r >> 16);
}

// ---------------- mask dtype detector ----------------
__global__ void detect_kernel(const unsigned char* __restrict__ m, int* __restrict__ flag) {
    __shared__ int cnt1;
    __shared__ int big;
    if (threadIdx.x == 0) { cnt1 = 0; big = 0; }
    __syncthreads();
    int c1 = 0, bg = 0;
    for (int i = threadIdx.x; i < 16384; i += 256) {
        unsigned char v = m[i];
        if (v) {
            if ((i & 3) == 1) c1++;
            if (v > 1) bg++;
        }
    }
    atomicAdd(&cnt1, c1);
    atomicAdd(&big, bg);
    __syncthreads();
    if (threadIdx.x == 0) {
        int f;
        if (big == 0) f = cnt1 ? 0 : 1;
        else          f = cnt1 ? 3 : 2;
        *flag = f;
    }
}

// ---------------- mask -> packed bitmask ----------------
#define MN_LOOP(PRED)                                                     \
    for (int row = wave; row < 65536; row += nw) {                        \
        size_t base = (size_t)row * 1024;                                 \
        u64 myw = 0;                                                      \
        _Pragma("unroll")                                                 \
        for (int kb = 0; kb < 16; ++kb) {                                 \
            size_t gi = base + kb * 64 + lane;                            \
            bool p = (PRED);                                              \
            u64 w = __ballot(p);                                          \
            if (lane == kb) myw = w;                                      \
        }                                                                 \
        if (lane < 16) MB[(size_t)row * 16 + lane] = myw;                 \
    }

__global__ __launch_bounds__(256) void masknorm_kernel(const void* __restrict__ mp,
                                                       const int* __restrict__ flagp,
                                                       u64* __restrict__ MB) {
    const int flag = *flagp;
    const int lane = threadIdx.x & 63;
    const int wave = blockIdx.x * 4 + (threadIdx.x >> 6);
    const int nw = gridDim.x * 4;
    if (flag == 0) {
        const unsigned char* m8 = (const unsigned char*)mp;
        MN_LOOP(m8[gi] != 0)
    } else if (flag == 1) {
        const int* m32 = (const int*)mp;
        MN_LOOP(m32[gi] != 0)
    } else if (flag == 2) {
        const unsigned* mf = (const unsigned*)mp;
        MN_LOOP((mf[gi] << 1) != 0)
    } else {
        const u16* mb = (const u16*)mp;
        MN_LOOP((mb[gi] & 0x7FFF) != 0)
    }
}

// ---------------- f32 -> bf16 cast of Q/K/V inputs ----------------
__global__ void cast3_kernel(const float* __restrict__ q, const float* __restrict__ k,
                             const float* __restrict__ v, u16* __restrict__ xq,
                             u16* __restrict__ xk, u16* __restrict__ xv) {
    const int n4 = 4 * 1024 * 1024 / 4;
    int stride = gridDim.x * blockDim.x;
    for (int i = blockIdx.x * blockDim.x + threadIdx.x; i < n4; i += stride) {
        float4 a = ((const float4*)q)[i];
        float4 b = ((const float4*)k)[i];
        float4 c = ((const float4*)v)[i];
        ((ushort4*)xq)[i] = make_ushort4(f2bf(a.x), f2bf(a.y), f2bf(a.z), f2bf(a.w));
        ((ushort4*)xk)[i] = make_ushort4(f2bf(b.x), f2bf(b.y), f2bf(b.z), f2bf(b.w));
        ((ushort4*)xv)[i] = make_ushort4(f2bf(c.x), f2bf(c.y), f2bf(c.z), f2bf(c.w));
    }
}

// ---------------- weight transpose + cast ----------------
__global__ __launch_bounds__(256) void wtrans_kernel(
    const float* __restrict__ W0, const float* __restrict__ W1,
    const float* __restrict__ W2, const float* __restrict__ W3,
    u16* __restrict__ T0, u16* __restrict__ T1, u16* __restrict__ T2, u16* __restrict__ T3) {
    const float* W = (blockIdx.z == 0) ? W0 : (blockIdx.z == 1) ? W1 : (blockIdx.z == 2) ? W2 : W3;
    u16* T = (blockIdx.z == 0) ? T0 : (blockIdx.z == 1) ? T1 : (blockIdx.z == 2) ? T2 : T3;
    __shared__ float t[64][65];
    const int n0 = blockIdx.x * 64, k0 = blockIdx.y * 64;
    const int tx = threadIdx.x, ty = threadIdx.y;
    for (int j = ty; j < 64; j += 4) t[j][tx] = W[(size_t)(k0 + j) * 1024 + n0 + tx];
    __syncthreads();
    for (int j = ty; j < 64; j += 4) T[(size_t)(n0 + j) * 1024 + k0 + tx] = f2bf(t[tx][j]);
}

// ================= GEMM core v2: BK=32, 3-buffer counted pipeline, swizzled LDS =================
// Tile 128x128, 32 k-steps. LDS per operand: 3 bufs x 128 rows x 32 cols (8KB) = 24KB; 48KB total.
// Staging: thread covers (row = site*64 + tid>>2, slot = tid&3); global source pre-swizzled
// slot_g = slot ^ ((row>>1)&3) so fragment reads (slot = l4 ^ ((row>>1)&3)) are <=2-way conflicts.
// Body t: issue stage(t+2) -> compute(t) -> vmcnt(4) [retires stage(t+1), a full body of slack]
// -> s_barrier. Never drains mid-loop.
__device__ __forceinline__ void gemm_core(const u16* __restrict__ A, const u16* __restrict__ Bt,
                                          u16* sA, u16* sB, f32x4 (&acc)[4][4],
                                          int tid, int bm, int bn) {
    const int lane = tid & 63, wid = tid >> 6;
    const int wr = wid >> 1, wc = wid & 1;
    const int l15 = lane & 15, l4 = lane >> 4;
    const int srow = tid >> 2, sslot = tid & 3;
    const int soff = (sslot ^ ((srow >> 1) & 3)) * 8;
    const u16* aSrc = A + (size_t)(bm * 128 + srow) * 1024 + soff;
    const u16* bSrc = Bt + (size_t)(bn * 128 + srow) * 1024 + soff;
    u16* const dA0 = sA + wid * 512;           // site0 dest (+buf*4096)
    u16* const dA1 = sA + 2048 + wid * 512;    // site1
    u16* const dB0 = sB + wid * 512;
    u16* const dB1 = sB + 2048 + wid * 512;

#define GSTAGE(BUF, T)                                                  \
    do {                                                                \
        GLL16(aSrc + (T) * 32, dA0 + (BUF) * 4096);                     \
        GLL16(aSrc + 65536 + (T) * 32, dA1 + (BUF) * 4096);             \
        GLL16(bSrc + (T) * 32, dB0 + (BUF) * 4096);                     \
        GLL16(bSrc + 65536 + (T) * 32, dB1 + (BUF) * 4096);             \
    } while (0)

#define GCOMPUTE(BUF)                                                             \
    do {                                                                          \
        bf16x8 af[4], bfv[4];                                                     \
        _Pragma("unroll")                                                         \
        for (int m = 0; m < 4; ++m) {                                             \
            const int rr = wr * 64 + m * 16 + l15;                                \
            af[m] = *(const bf16x8*)(sA + (BUF) * 4096 + rr * 32 +                \
                                     ((l4 ^ ((rr >> 1) & 3)) * 8));               \
        }                                                                         \
        _Pragma("unroll")                                                         \
        for (int n = 0; n < 4; ++n) {                                             \
            const int rr = wc * 64 + n * 16 + l15;                                \
            bfv[n] = *(const bf16x8*)(sB + (BUF) * 4096 + rr * 32 +               \
                                      ((l4 ^ ((rr >> 1) & 3)) * 8));              \
        }                                                                         \
        _Pragma("unroll")                                                         \
        for (int m = 0; m < 4; ++m)                                               \
            _Pragma("unroll")                                                     \
            for (int n = 0; n < 4; ++n)                                           \
                acc[m][n] = __builtin_amdgcn_mfma_f32_16x16x32_bf16(af[m], bfv[n], acc[m][n], 0, 0, 0); \
    } while (0)

#define GBODY(T, BUF, NBUF, WSTR)                                       \
    do {                                                                \
        if ((T) + 2 < 32) {                                             \
            GSTAGE(NBUF, (T) + 2);                                      \
            __builtin_amdgcn_sched_barrier(0);                          \
        }                                                               \
        GCOMPUTE(BUF);                                                  \
        if ((T) + 1 < 32) {                                             \
            asm volatile(WSTR ::: "memory");                            \
            __builtin_amdgcn_sched_barrier(0);                          \
            __builtin_amdgcn_s_barrier();                               \
            __builtin_amdgcn_sched_barrier(0);                          \
        }                                                               \
    } while (0)

    // prologue: stage tiles 0,1; vmcnt(4) retires stage(0)'s 4 GLL16.
    GSTAGE(0, 0);
    GSTAGE(1, 1);
    __builtin_amdgcn_sched_barrier(0);
    asm volatile("s_waitcnt vmcnt(4)" ::: "memory");
    __builtin_amdgcn_sched_barrier(0);
    __builtin_amdgcn_s_barrier();
    __builtin_amdgcn_sched_barrier(0);

    for (int it = 0; it < 10; ++it) {
        const int t0 = it * 3;
        GBODY(t0 + 0, 0, 2, "s_waitcnt vmcnt(4)");
        GBODY(t0 + 1, 1, 0, "s_waitcnt vmcnt(4)");
        GBODY(t0 + 2, 2, 1, "s_waitcnt vmcnt(4)");
    }
    GBODY(30, 0, 2, "s_waitcnt vmcnt(0)");   // no stage issued; drain stage(31)
    GBODY(31, 1, 0, "s_waitcnt vmcnt(0)");   // guards disable stage/wait
#undef GBODY
#undef GCOMPUTE
#undef GSTAGE
}

// ---------------- merged QKV GEMM: z=0 Q (scaled), z=1 K, z=2 V (transposed out via LDS) ----------------
__global__ __launch_bounds__(256, 3) void qkv_gemm(
    const u16* __restrict__ XQ, const u16* __restrict__ XK, const u16* __restrict__ XV,
    const u16* __restrict__ WQT, const u16* __restrict__ WKT, const u16* __restrict__ WVT,
    const float* __restrict__ bq, const float* __restrict__ bk, const float* __restrict__ bv,
    u16* __restrict__ QS, u16* __restrict__ KS, u16* __restrict__ VT) {
    __shared__ __align__(16) u16 smem[24576];   // [0,12288) A bufs; [12288,24576) B bufs
    const int z = blockIdx.z;
    const u16* A  = (z == 0) ? XQ : (z == 1) ? XK : XV;
    const u16* Bt = (z == 0) ? WQT : (z == 1) ? WKT : WVT;
    const float* bias = (z == 0) ? bq : (z == 1) ? bk : bv;
    const int tid = threadIdx.x, lane = tid & 63, wid = tid >> 6;
    const int bm = blockIdx.y, bn = blockIdx.x;
    const int wr = wid >> 1, wc = wid & 1;
    const int l15 = lane & 15, l4 = lane >> 4;

    f32x4 acc[4][4] = {};
    gemm_core(A, Bt, smem, smem + 12288, acc, tid, bm, bn);

    if (z == 2) {
        // transpose 128x128 tile through LDS, then coalesced 16B stores into VT
        __syncthreads();
        u16* tl = smem;                          // 128 x 132 u16 = 16896 <= 24576
#pragma unroll
        for (int n = 0; n < 4; ++n) {
            const int cl = wc * 64 + n * 16 + l15;
            const float bv_ = bias[bn * 128 + cl];
#pragma unroll
            for (int m = 0; m < 4; ++m)
#pragma unroll
                for (int j = 0; j < 4; ++j) {
                    const int rl = wr * 64 + m * 16 + l4 * 4 + j;
                    tl[cl * 132 + rl] = f2bf(acc[m][n][j] + bv_);
                }
        }
        __syncthreads();
        const int bb = bm >> 3, k0 = (bm & 7) * 128;
#pragma unroll
        for (int i = 0; i < 8; ++i) {
            const int idx = i * 256 + tid;
            const int row = idx >> 4, col16 = idx & 15;
            const int cg = bn * 128 + row;
            const int hh = cg >> 6, dd = cg & 63;
            bf16x8 v = *(const bf16x8*)(tl + row * 132 + col16 * 8);
            *(bf16x8*)(VT + ((size_t)((bb * 16 + hh) * 64 + dd)) * 1024 + k0 + col16 * 8) = v;
        }
    } else {
        u16* outp = (z == 0) ? QS : KS;
        const float scale = (z == 0) ? 0.125f : 1.0f;
#pragma unroll
        for (int n = 0; n < 4; ++n) {
            const int c = bn * 128 + wc * 64 + n * 16 + l15;
            const float bv_ = bias[c];
#pragma unroll
            for (int m = 0; m < 4; ++m)
#pragma unroll
                for (int j = 0; j < 4; ++j) {
                    const int r = bm * 128 + wr * 64 + m * 16 + l4 * 4 + j;
                    outp[(size_t)r * 1024 + c] = f2bf((acc[m][n][j] + bv_) * scale);
                }
        }
    }
}

// ---------------- output-projection GEMM (+bias +residual, f32 out) ----------------
__global__ __launch_bounds__(256, 3) void gemm_out(
    const u16* __restrict__ A, const u16* __restrict__ Bt, const float* __restrict__ bias,
    float* __restrict__ outp, const float* __restrict__ resid) {
    __shared__ __align__(16) u16 smem[24576];
    const int tid = threadIdx.x, lane = tid & 63, wid = tid >> 6;
    const int bm = blockIdx.y, bn = blockIdx.x;
    const int wr = wid >> 1, wc = wid & 1;
    const int l15 = lane & 15, l4 = lane >> 4;

    f32x4 acc[4][4] = {};
    gemm_core(A, Bt, smem, smem + 12288, acc, tid, bm, bn);

#pragma unroll
    for (int n = 0; n < 4; ++n) {
        const int c = bn * 128 + wc * 64 + n * 16 + l15;
        const float bv = bias[c];
#pragma unroll
        for (int m = 0; m < 4; ++m)
#pragma unroll
            for (int j = 0; j < 4; ++j) {
                const int r = bm * 128 + wr * 64 + m * 16 + l4 * 4 + j;
                outp[(size_t)r * 1024 + c] = acc[m][n][j] + bv + resid[(size_t)r * 1024 + c];
            }
    }
}

// ---------------- fused geometry attention v7 (unchanged from round 9) ----------------
__global__ __launch_bounds__(256, 4) void attn_kernel(
    const u16* __restrict__ Qs, const u16* __restrict__ Ks, const u16* __restrict__ Vt,
    const float* __restrict__ geom, const u64* __restrict__ MBw,
    u16* __restrict__ AO) {
    __shared__ __align__(16) u16 lds[14336];

    const int g = blockIdx.x;
    const int tt = (g & 7) * 128 + (g >> 3);
    const int qb = tt & 15;
    const int bhid = tt >> 4;
    const int b = bhid >> 4, h = bhid & 15;
    const int q0 = qb * 64;

    const int tid = threadIdx.x, lane = tid & 63, wid = tid >> 6;
    const int l15 = lane & 15, l4 = lane >> 4;
    const int qrow = q0 + wid * 16;
    const size_t bh = (size_t)bhid;

    const u16* qp = Qs + (size_t)(b * 1024 + qrow + l15) * 1024 + h * 64 + l4 * 8;
    bf16x8 aq0 = *(const bf16x8*)qp;
    bf16x8 aq1 = *(const bf16x8*)(qp + 32);

    const int kr = tid >> 3, ks = tid & 7;
    const int kgr = (kr & 15) * 2 + (kr >> 4);
    const u16* ksrc = Ks + (size_t)(b * 1024 + kgr) * 1024 + h * 64 + ((ks ^ ((kr >> 1) & 7)) * 8);
    const int vr = tid >> 2, vs = tid & 3;
    const u16* vsrc = Vt + (bh * 64 + vr) * 1024 + ((vs ^ ((vr >> 1) & 3)) * 8);
    u16* const KD0 = lds + 0    + wid * 512;
    u16* const KD1 = lds + 2048 + wid * 512;
    u16* const KD2 = lds + 4096 + wid * 512;
    u16* const VD0 = lds + 6144 + 0    + wid * 512;
    u16* const VD1 = lds + 6144 + 2048 + wid * 512;
    u16* const VD2 = lds + 6144 + 4096 + wid * 512;
    u16* const pw  = lds + 12288 + wid * 512;

    const float* gbase = geom + (bh * 1024 + qrow + l4 * 4) * 1024 + l15 * 2;
    const unsigned* mb32 = (const unsigned*)(MBw + (bh * 1024 + qrow + l4 * 4) * 16);

    f32x4 o[4] = {};
    float m_run[4], l_run[4];
#pragma unroll
    for (int j = 0; j < 4; ++j) { m_run[j] = -1e30f; l_run[j] = 0.f; }

    f32x2 gpA[4], gpB[4];
    unsigned mkA[4], mkB[4];

    GLL16(ksrc, KD0);
    GLL16(vsrc, VD0);
    GLL16(ksrc + 32768, KD1);
    GLL16(vsrc + 32, VD1);
    __builtin_amdgcn_sched_barrier(0);
#pragma unroll
    for (int j = 0; j < 4; ++j) {
        gpA[j] = *(const f32x2*)(gbase + j * 1024);
        mkA[j] = mb32[j * 32];
    }
    __builtin_amdgcn_sched_barrier(0);
    asm volatile("s_waitcnt vmcnt(10)" ::: "memory");
    __builtin_amdgcn_sched_barrier(0);
    __builtin_amdgcn_s_barrier();
    __builtin_amdgcn_sched_barrier(0);

#define BODY(T, GC, GN, MC, MN, KBC, VBC, KDN, VDN, WSTR)                                \
    do {                                                                                 \
        if ((T) + 2 < 32) {                                                              \
            GLL16(ksrc + (size_t)((T) + 2) * 32768, KDN);                                \
            GLL16(vsrc + ((T) + 2) * 32, VDN);                                           \
            __builtin_amdgcn_sched_barrier(0);                                           \
        }                                                                                \
        if ((T) + 1 < 32) {                                                              \
            _Pragma("unroll")                                                            \
            for (int j = 0; j < 4; ++j) {                                                \
                GN[j] = *(const f32x2*)(gbase + j * 1024 + ((T) + 1) * 32);              \
                MN[j] = mb32[j * 32 + (T) + 1];                                          \
            }                                                                            \
            __builtin_amdgcn_sched_barrier(0);                                           \
        }                                                                                \
        f32x4 s0, s1;                                                                    \
        __builtin_amdgcn_s_setprio(1);                                                   \
        {                                                                                \
            const int rr = l15, swz = (rr >> 1) & 7;                                     \
            bf16x8 k0 = *(const bf16x8*)((KBC) + rr * 64 + ((l4 ^ swz) * 8));            \
            bf16x8 k1 = *(const bf16x8*)((KBC) + rr * 64 + (((4 + l4) ^ swz) * 8));      \
            f32x4 z = {};                                                                \
            z = __builtin_amdgcn_mfma_f32_16x16x32_bf16(aq0, k0, z, 0, 0, 0);            \
            s0 = __builtin_amdgcn_mfma_f32_16x16x32_bf16(aq1, k1, z, 0, 0, 0);           \
        }                                                                                \
        {                                                                                \
            const int rr = 16 + l15, swz = (rr >> 1) & 7;                                \
            bf16x8 k0 = *(const bf16x8*)((KBC) + rr * 64 + ((l4 ^ swz) * 8));            \
            bf16x8 k1 = *(const bf16x8*)((KBC) + rr * 64 + (((4 + l4) ^ swz) * 8));      \
            f32x4 z = {};                                                                \
            z = __builtin_amdgcn_mfma_f32_16x16x32_bf16(aq0, k0, z, 0, 0, 0);            \
            s1 = __builtin_amdgcn_mfma_f32_16x16x32_bf16(aq1, k1, z, 0, 0, 0);           \
        }                                                                                \
        __builtin_amdgcn_s_setprio(0);                                                   \
        float sclv[4];                                                                   \
        _Pragma("unroll")                                                                \
        for (int j = 0; j < 4; ++j) {                                                    \
            float a0 = s0[j], a1 = s1[j];                                                \
            float mt = fmaxf(a0, a1);                                                    \
            mt = fmaxf(mt, __shfl_xor(mt, 1, 16));                                       \
            mt = fmaxf(mt, __shfl_xor(mt, 2, 16));                                       \
            mt = fmaxf(mt, __shfl_xor(mt, 4, 16));                                       \
            mt = fmaxf(mt, __shfl_xor(mt, 8, 16));                                       \
            float mn = fmaxf(m_run[j], mt);                                              \
            float scl = __expf(m_run[j] - mn);                                           \
            m_run[j] = mn;                                                               \
            unsigned mb2 = (MC[j] >> (l15 * 2)) & 3u;                                    \
            f32x2 gv = GC[j];                                                            \
            float p0 = (mb2 & 1u) ? 0.f : __expf(a0 - mn) * fmaxf(gv[0], 1e-6f);         \
            float p1 = (mb2 & 2u) ? 0.f : __expf(a1 - mn) * fmaxf(gv[1], 1e-6f);         \
            float rs = p0 + p1;                                                          \
            rs += __shfl_xor(rs, 1, 16);                                                 \
            rs += __shfl_xor(rs, 2, 16);                                                 \
            rs += __shfl_xor(rs, 4, 16);                                                 \
            rs += __shfl_xor(rs, 8, 16);                                                 \
            l_run[j] = l_run[j] * scl + rs;                                              \
            sclv[j] = scl;                                                               \
            const int row = l4 * 4 + j;                                                  \
            const int slot4 = (l15 & 3) | ((((l15 >> 2) ^ l4) & 3) << 2);                \
            unsigned pk = (unsigned)f2bf(p0) | ((unsigned)f2bf(p1) << 16);               \
            *(unsigned*)(pw + row * 32 + slot4 * 2) = pk;                                \
        }                                                                                \
        _Pragma("unroll")                                                                \
        for (int df = 0; df < 4; ++df) {                                                 \
            f32x4 tv = o[df];                                                            \
            _Pragma("unroll")                                                            \
            for (int j = 0; j < 4; ++j) tv[j] *= sclv[j];                                \
            o[df] = tv;                                                                  \
        }                                                                                \
        {                                                                                \
            const int blk = (l4 ^ (l15 >> 2)) & 3;                                       \
            bf16x8 pa = *(const bf16x8*)(pw + l15 * 32 + blk * 8);                       \
            __builtin_amdgcn_s_setprio(1);                                               \
            _Pragma("unroll")                                                            \
            for (int df = 0; df < 4; ++df) {                                             \
                const int rr = df * 16 + l15, vswz = (rr >> 1) & 3;                      \
                bf16x8 v0 = *(const bf16x8*)((VBC) + rr * 32 + ((l4 ^ vswz) * 8));       \
                o[df] = __builtin_amdgcn_mfma_f32_16x16x32_bf16(pa, v0, o[df], 0, 0, 0); \
            }                                                                            \
            __builtin_amdgcn_s_setprio(0);                                               \
        }                                                                                \
        if ((T) + 1 < 32) {                                                              \
            asm volatile(WSTR ::: "memory");                                             \
            __builtin_amdgcn_sched_barrier(0);                                           \
            __builtin_amdgcn_s_barrier();                                                \
            __builtin_amdgcn_sched_barrier(0);                                           \
        }                                                                                \
    } while (0)

    for (int it = 0; it < 5; ++it) {
        const int t0 = it * 6;
        BODY(t0 + 0, gpA, gpB, mkA, mkB, (lds + 0),    (lds + 6144),        KD2, VD2, "s_waitcnt vmcnt(10)");
        BODY(t0 + 1, gpB, gpA, mkB, mkA, (lds + 2048), (lds + 6144 + 2048), KD0, VD0, "s_waitcnt vmcnt(10)");
        BODY(t0 + 2, gpA, gpB, mkA, mkB, (lds + 4096), (lds + 6144 + 4096), KD1, VD1, "s_waitcnt vmcnt(10)");
        BODY(t0 + 3, gpB, gpA, mkB, mkA, (lds + 0),    (lds + 6144),        KD2, VD2, "s_waitcnt vmcnt(10)");
        BODY(t0 + 4, gpA, gpB, mkA, mkB, (lds + 2048), (lds + 6144 + 2048), KD0, VD0, "s_waitcnt vmcnt(10)");
        BODY(t0 + 5, gpB, gpA, mkB, mkA, (lds + 4096), (lds + 6144 + 4096), KD1, VD1, "s_waitcnt vmcnt(10)");
    }
    BODY(30, gpA, gpB, mkA, mkB, (lds + 0),    (lds + 6144),        KD2, VD2, "s_waitcnt vmcnt(8)");
    BODY(31, gpB, gpA, mkB, mkA, (lds + 2048), (lds + 6144 + 2048), KD0, VD0, "s_waitcnt vmcnt(8)");
#undef BODY

    float inv[4];
#pragma unroll
    for (int j = 0; j < 4; ++j) inv[j] = 1.0f / l_run[j];
#pragma unroll
    for (int p = 0; p < 2; ++p) {
#pragma unroll
        for (int df2 = 0; df2 < 2; ++df2) {
            const int df = p * 2 + df2;
#pragma unroll
            for (int j = 0; j < 4; ++j)
                pw[(l4 * 4 + j) * 32 + df2 * 16 + l15] = f2bf(o[df][j] * inv[j]);
        }
        const int er = lane >> 2, ec = lane & 3;
        bf16x8 val = *(const bf16x8*)(pw + er * 32 + ec * 8);
        *(bf16x8*)(AO + (size_t)(b * 1024 + qrow + er) * 1024 + h * 64 + p * 32 + ec * 8) = val;
    }
}

// ---------------- LayerNorm over rows of Y (f32) ----------------
__global__ __launch_bounds__(256) void ln_kernel(const float* __restrict__ Y,
                                                 const float* __restrict__ gamma,
                                                 const float* __restrict__ beta,
                                                 float* __restrict__ out) {
    __shared__ float red[8];
    const int r = blockIdx.x, tid = threadIdx.x, lane = tid & 63, wid = tid >> 6;
    float4 v = ((const float4*)(Y + (size_t)r * 1024))[tid];
    float s = v.x + v.y + v.z + v.w;
    float q = v.x * v.x + v.y * v.y + v.z * v.z + v.w * v.w;
    for (int d = 1; d < 64; d <<= 1) {
        s += __shfl_xor(s, d, 64);
        q += __shfl_xor(q, d, 64);
    }
    if (lane == 0) { red[wid] = s; red[4 + wid] = q; }
    __syncthreads();
    float ts = red[0] + red[1] + red[2] + red[3];
    float tq = red[4] + red[5] + red[6] + red[7];
    float mu = ts * (1.f / 1024.f);
    float var = tq * (1.f / 1024.f) - mu * mu;
    float rstd = rsqrtf(var + 1e-5f);
    float4 gg = ((const float4*)gamma)[tid];
    float4 be = ((const float4*)beta)[tid];
    float4 ov;
    ov.x = (v.x - mu) * rstd * gg.x + be.x;
    ov.y = (v.y - mu) * rstd * gg.y + be.y;
    ov.z = (v.z - mu) * rstd * gg.z + be.z;
    ov.w = (v.w - mu) * rstd * gg.w + be.w;
    ((float4*)(out + (size_t)r * 1024))[tid] = ov;
}

extern "C" void kernel_launch(void* const* d_in, const int* in_sizes, int n_in,
                              void* d_out, int out_size, void* d_ws, size_t ws_size,
                              hipStream_t stream) {
    const float* queries = (const float*)d_in[0];
    const float* keys    = (const float*)d_in[1];
    const float* values  = (const float*)d_in[2];
    const float* geom    = (const float*)d_in[3];
    const void*  mask    = d_in[4];
    const float* Wq = (const float*)d_in[5];  const float* bq = (const float*)d_in[6];
    const float* Wk = (const float*)d_in[7];  const float* bk = (const float*)d_in[8];
    const float* Wv = (const float*)d_in[9];  const float* bv = (const float*)d_in[10];
    const float* Wo = (const float*)d_in[11]; const float* bo = (const float*)d_in[12];
    const float* gamma = (const float*)d_in[13];
    const float* beta  = (const float*)d_in[14];

    char* ws = (char*)d_ws;
    const size_t MB_ = 1024 * 1024;
    u16* XQ  = (u16*)(ws + 0);
    u16* XK  = (u16*)(ws + 8 * MB_);
    u16* XV  = (u16*)(ws + 16 * MB_);
    u16* WQT = (u16*)(ws + 24 * MB_);
    u16* WKT = (u16*)(ws + 26 * MB_);
    u16* WVT = (u16*)(ws + 28 * MB_);
    u16* WOT = (u16*)(ws + 30 * MB_);
    u16* QS  = (u16*)(ws + 32 * MB_);
    u16* KS  = (u16*)(ws + 40 * MB_);
    u16* VT  = (u16*)(ws + 48 * MB_);
    u16* AO  = (u16*)(ws + 56 * MB_);
    u64* MBITS = (u64*)(ws + 16 * MB_);  // reuses XV (dead after qkv_gemm)
    float* Y = (float*)(ws + 0);         // reuses XQ/XK region (dead by then)
    int* FLAG = (int*)(ws + 64 * MB_);

    detect_kernel<<<1, 256, 0, stream>>>((const unsigned char*)mask, FLAG);
    cast3_kernel<<<1024, 256, 0, stream>>>(queries, keys, values, XQ, XK, XV);
    wtrans_kernel<<<dim3(16, 16, 4), dim3(64, 4), 0, stream>>>(Wq, Wk, Wv, Wo, WQT, WKT, WVT, WOT);
    qkv_gemm<<<dim3(8, 32, 3), 256, 0, stream>>>(XQ, XK, XV, WQT, WKT, WVT, bq, bk, bv, QS, KS, VT);
    masknorm_kernel<<<4096, 256, 0, stream>>>(mask, FLAG, MBITS);
    attn_kernel<<<1024, 256, 0, stream>>>(QS, KS, VT, geom, MBITS, AO);
    gemm_out<<<dim3(8, 32), 256, 0, stream>>>(AO, WOT, bo, Y, queries);
    ln_kernel<<<4096, 256, 0, stream>>>(Y, gamma, beta, (float*)d_out);
}